// Round 18
// baseline (275.923 us; speedup 1.0000x reference)
//
#include <hip/hip_runtime.h>
#include <math.h>

#define HH 256
#define WW 256
#define BATCH 8
#define HWSZ 65536
#define BN_N 524288.0f  // BATCH*HWSZ
#define NSLOT 64        // stat-slot spreading factor

typedef __attribute__((ext_vector_type(8))) short short8;
typedef __attribute__((ext_vector_type(4))) float floatx4;

// round-half-up bf16 pack: 2 VALU ops, max err 0.5 ulp
__device__ __forceinline__ unsigned short f2bf(float f) {
  union { float f; unsigned int u; } v; v.f = f;
  return (unsigned short)((v.u + 0x8000u) >> 16);
}
// pack two fp32 -> bf16x2 (lo=a, hi=d): 5 VALU ops
__device__ __forceinline__ unsigned int pack2bf(float a, float d) {
  union { float f; unsigned int u; } va, vd; va.f = a; vd.f = d;
  return ((va.u + 0x8000u) >> 16) | ((vd.u + 0x8000u) & 0xffff0000u);
}
__device__ __forceinline__ float bf2f(unsigned short u) {
  union { unsigned int u; float f; } v; v.u = ((unsigned int)u) << 16;
  return v.f;
}

// ---- conv1 as im2col MFMA, R=4 (blocks 0..2047) + wf prep (2048..2407) ----
// Stage 6 rows x 66 px (1.5x redundancy, was 2.0x at R=2); 8 MFMA/wave.
__global__ __launch_bounds__(256) void conv1_mfma(
    const float* __restrict__ img, const float* __restrict__ w1,
    const float* __restrict__ bias, unsigned short* __restrict__ out,
    float* __restrict__ totals1,
    const float* __restrict__ w2, const float* __restrict__ w3,
    unsigned short* __restrict__ wf2, unsigned short* __restrict__ wf3)
{
  const int lin = blockIdx.x;
  if (lin >= 2048) {  // ---- prep path: 360 blocks cover 92160 elems ----
    int idx = (lin - 2048) * 256 + threadIdx.x;
    if (idx < 18432) {  // conv2: CIN=32, COUT=64, KC=1, NG=4
      const int j = idx & 7;
      const int lane = (idx >> 3) & 63;
      int rest = idx >> 9;
      const int ng = rest % 4;
      const int tap = rest / 4;
      const int cout = ng * 16 + (lane & 15);
      const int cin = ((lane >> 4) << 3) + j;
      wf2[idx] = f2bf(w2[((size_t)cout * 32 + cin) * 9 + tap]);
    } else {            // conv3: CIN=64, COUT=128, KC=2, NG=8
      idx -= 18432;
      if (idx >= 73728) return;
      const int j = idx & 7;
      const int lane = (idx >> 3) & 63;
      int rest = idx >> 9;
      const int ng = rest % 8; rest /= 8;
      const int kc = rest & 1;
      const int tap = rest >> 1;
      const int cout = ng * 16 + (lane & 15);
      const int cin = kc * 32 + ((lane >> 4) << 3) + j;
      wf3[idx] = f2bf(w3[((size_t)cout * 64 + cin) * 9 + tap]);
    }
    return;
  }

  const int tid = threadIdx.x, lane = tid & 63, wv = tid >> 6;
  const int wave_m = wv >> 1, wave_n = wv & 1;
  const int xcd = lin & 7, slot = lin >> 3;
  const int b = slot >> 5;            // 32 slots per batch
  const int rem = slot & 31;
  const int h0 = ((xcd << 3) + (rem >> 2)) * 4;
  const int w0 = (rem & 3) * 64;

  __shared__ __align__(16) unsigned short simg[6 * 66 * 4];  // [row][px][3ch+pad]
  __shared__ __align__(16) unsigned short swf[2 * 64 * 8];   // conv1 B-frags
  __shared__ float red2[2][4][16];                           // [s|q][wv][li]

  for (int t = tid; t < (6 * 66 * 4) / 2; t += 256)
    ((unsigned int*)simg)[t] = 0u;
  {
    const int t0 = tid * 4;
    #pragma unroll
    for (int u = 0; u < 4; ++u) {
      const int idx = t0 + u;
      const int j = idx & 7, l8 = (idx >> 3) & 63, nt = idx >> 9;
      const int k = ((l8 >> 4) << 3) + j;
      const int cout = nt * 16 + (l8 & 15);
      swf[idx] = (k < 27) ? f2bf(w1[cout * 27 + k]) : (unsigned short)0;
    }
  }
  __syncthreads();
  for (int t = tid; t < 3 * 6 * 66; t += 256) {
    const int ci = t / 396, r2 = t - ci * 396;
    const int r = r2 / 66, px = r2 - r * 66;
    const int hi = h0 + r - 1, wi = w0 + px - 1;
    if ((unsigned)hi < 256u && (unsigned)wi < 256u)
      simg[(r * 66 + px) * 4 + ci] =
          f2bf(img[((size_t)(b * 3 + ci) * 256 + hi) * 256 + wi]);
  }
  __syncthreads();

  const int j15 = lane & 15, q4 = lane >> 4;
  int off[8];
  #pragma unroll
  for (int j = 0; j < 8; ++j) {
    const int k = q4 * 8 + j;
    const int ci = k / 9, tap = k - ci * 9;
    const int dh = tap / 3, dw = tap - dh * 3;
    off[j] = (dh * 66 + dw) * 4 + ci;
  }
  const int base_px = wave_m * 32 + j15;
  const short8 bg = *(const short8*)&swf[(wave_n * 64 + lane) * 8];

  floatx4 acc[4][2];
  #pragma unroll
  for (int rr = 0; rr < 4; ++rr)
    #pragma unroll
    for (int mf = 0; mf < 2; ++mf) {
      acc[rr][mf] = (floatx4){0.f, 0.f, 0.f, 0.f};
      union { short8 v; unsigned short e[8]; } a;
      const int ab = (rr * 66 + base_px + mf * 16) * 4;
      #pragma unroll
      for (int j = 0; j < 8; ++j) a.e[j] = simg[ab + off[j]];
      acc[rr][mf] = __builtin_amdgcn_mfma_f32_16x16x32_bf16(a.v, bg, acc[rr][mf], 0, 0, 0);
    }

  float sa = 0.f, qa = 0.f;
  const float bv = bias[wave_n * 16 + j15];
  #pragma unroll
  for (int rr = 0; rr < 4; ++rr) {
    const size_t orow = ((size_t)(b * 256 + (h0 + rr)) * 256 + w0);
    #pragma unroll
    for (int mf = 0; mf < 2; ++mf)
      #pragma unroll
      for (int r4 = 0; r4 < 4; ++r4) {
        float y = acc[rr][mf][r4] + bv;
        sa += y; qa += y * y;
        const int p = wave_m * 32 + mf * 16 + q4 * 4 + r4;
        out[(orow + p) * 32 + wave_n * 16 + j15] = f2bf(y);
      }
  }
  sa += __shfl_xor(sa, 16); sa += __shfl_xor(sa, 32);
  qa += __shfl_xor(qa, 16); qa += __shfl_xor(qa, 32);
  if (lane < 16) { red2[0][wv][lane] = sa; red2[1][wv][lane] = qa; }
  __syncthreads();
  if (tid < 64) {
    const int c = tid >> 1, jj = tid & 1;
    const int wn = c >> 4, li = c & 15;
    const float r = red2[jj][wn][li] + red2[jj][wn + 2][li];
    atomicAdd(&totals1[(((size_t)(lin & (NSLOT - 1)) * 2 + jj)) * 32 + c], r);
  }
}

// ---- MFMA conv: 64px x R ROWS x COUT per block, PADDED affine LDS ---------
template<int CIN, int COUT, int R, bool WRITE_OUT, int MINW>
__global__ __launch_bounds__(256, MINW) void conv_mfma(
    const unsigned short* __restrict__ in, const unsigned short* __restrict__ wf,
    const float* __restrict__ bias,
    const float* __restrict__ totals_in, const float* __restrict__ gamma_in,
    const float* __restrict__ beta_in,
    unsigned short* __restrict__ out, float* __restrict__ totals_out)
{
  constexpr int KC = CIN / 32;
  constexpr int NG = COUT / 16;
  constexpr int NF = COUT / 32;
  constexpr int CH8 = CIN / 8;
  constexpr int CH8_LOG = (CH8 == 4) ? 2 : 3;
  constexpr int CPAD = CIN + 8;
  constexpr int GRP = 256 / CIN;        // fold groups
  constexpr int SPG = NSLOT / GRP;      // slots per group
  constexpr int ROWS = R + 2;           // staged rows
  constexpr int HT8 = (256 / R) / 8;    // h-tiles per XCD per batch
  constexpr int SLB = (256 / R) / 2;    // slots per batch

  const int tid = threadIdx.x, lane = tid & 63, wv = tid >> 6;
  const int wave_m = wv >> 1, wave_n = wv & 1;

  const int lin = blockIdx.x;
  const int xcd = lin & 7, slot = lin >> 3;
  const int b = slot / SLB;
  const int rem = slot % SLB;
  const int h0 = (xcd * HT8 + (rem >> 2)) * R;
  const int w0 = (rem & 3) * 64;
  const size_t inb = (size_t)b * HWSZ * CIN;

  __shared__ __align__(16) unsigned short lds[ROWS * 66 * CPAD];
  __shared__ __align__(16) float scsh[2][CIN];

  // parallel BN fold: 256 threads cover NSLOT slots in GRP groups
  {
    const int c = tid % CIN, g = tid / CIN;
    float ps = 0.f, pq = 0.f;
    #pragma unroll
    for (int i = 0; i < SPG; ++i) {
      const int sl = g * SPG + i;
      ps += totals_in[((size_t)sl * 2 + 0) * CIN + c];
      pq += totals_in[((size_t)sl * 2 + 1) * CIN + c];
    }
    float* pf = (float*)lds;  // [2][GRP][CIN] partials (staging overwrites later)
    pf[(0 * GRP + g) * CIN + c] = ps;
    pf[(1 * GRP + g) * CIN + c] = pq;
    __syncthreads();
    if (tid < CIN) {
      float s = 0.f, q = 0.f;
      #pragma unroll
      for (int g2 = 0; g2 < GRP; ++g2) {
        s += pf[(0 * GRP + g2) * CIN + tid];
        q += pf[(1 * GRP + g2) * CIN + tid];
      }
      const float mean = s / BN_N;
      const float var = q / BN_N - mean * mean;
      const float rstd = rsqrtf(var + 1e-5f);
      const float sc = gamma_in[tid] * rstd;
      scsh[0][tid] = sc;
      scsh[1][tid] = beta_in[tid] - mean * sc;
    }
    __syncthreads();
  }

  // staging: fixed ck per thread; scale/shift regs loaded ONCE
  {
    const int ck = tid & (CH8 - 1);
    const float4 s0 = *(const float4*)&scsh[0][ck * 8];
    const float4 s1 = *(const float4*)&scsh[0][ck * 8 + 4];
    const float4 t0 = *(const float4*)&scsh[1][ck * 8];
    const float4 t1 = *(const float4*)&scsh[1][ck * 8 + 4];
    const float scs[8] = {s0.x, s0.y, s0.z, s0.w, s1.x, s1.y, s1.z, s1.w};
    const float shs[8] = {t0.x, t0.y, t0.z, t0.w, t1.x, t1.y, t1.z, t1.w};
    for (int rpx = tid >> CH8_LOG; rpx < ROWS * 66; rpx += 256 >> CH8_LOG) {
      const int r = rpx / 66, px = rpx - r * 66;
      const int hi = h0 + r - 1, wi = w0 - 1 + px;
      uint4 v = make_uint4(0u, 0u, 0u, 0u);
      if ((unsigned)hi < 256u && (unsigned)wi < 256u) {
        uint4 raw = *(const uint4*)&in[inb + ((size_t)hi * 256 + wi) * CIN + ck * 8];
        unsigned int* u = (unsigned int*)&raw;
        unsigned int* o = (unsigned int*)&v;
        #pragma unroll
        for (int p = 0; p < 4; ++p) {
          float a = bf2f((unsigned short)(u[p] & 0xffff));
          float d = bf2f((unsigned short)(u[p] >> 16));
          float ya = a * scs[2 * p] + shs[2 * p];
          float yd = d * scs[2 * p + 1] + shs[2 * p + 1];
          ya = fmaxf(ya, 0.01f * ya);
          yd = fmaxf(yd, 0.01f * yd);
          o[p] = pack2bf(ya, yd);
        }
      }
      *(uint4*)&lds[rpx * CPAD + ck * 8] = v;
    }
  }
  __syncthreads();

  const int j15 = lane & 15, q4 = lane >> 4;
  const int base_px = wave_m * 32 + j15;
  const unsigned short* abase = &lds[base_px * CPAD + q4 * 8];

  floatx4 acc[R][2][NF];
  #pragma unroll
  for (int rr = 0; rr < R; ++rr)
    #pragma unroll
    for (int mf = 0; mf < 2; ++mf)
      #pragma unroll
      for (int nf = 0; nf < NF; ++nf) acc[rr][mf][nf] = (floatx4){0.f, 0.f, 0.f, 0.f};

  #pragma unroll
  for (int dh = 0; dh < 3; ++dh) {
    #pragma unroll
    for (int dw = 0; dw < 3; ++dw) {
      #pragma unroll
      for (int kc = 0; kc < KC; ++kc) {
        const int tap = dh * 3 + dw;
        short8 bg[NF];
        #pragma unroll
        for (int nf = 0; nf < NF; ++nf)
          bg[nf] = *(const short8*)&wf[((((tap * KC + kc) * NG) + wave_n * NF + nf) * 64 + lane) * 8];
        #pragma unroll
        for (int rr = 0; rr < R; ++rr) {
          short8 a[2];
          #pragma unroll
          for (int mf = 0; mf < 2; ++mf)
            a[mf] = *(const short8*)&abase[((rr + dh) * 66 + dw + mf * 16) * CPAD + kc * 32];
          #pragma unroll
          for (int mf = 0; mf < 2; ++mf)
            #pragma unroll
            for (int nf = 0; nf < NF; ++nf)
              acc[rr][mf][nf] = __builtin_amdgcn_mfma_f32_16x16x32_bf16(a[mf], bg[nf], acc[rr][mf][nf], 0, 0, 0);
        }
      }
    }
  }

  float bv[NF], sa[NF], qa[NF];
  #pragma unroll
  for (int nf = 0; nf < NF; ++nf) {
    bv[nf] = bias[wave_n * (COUT / 2) + nf * 16 + j15];
    sa[nf] = 0.f; qa[nf] = 0.f;
  }
  #pragma unroll
  for (int rr = 0; rr < R; ++rr) {
    const size_t orow = ((size_t)(b * 256 + (h0 + rr)) * 256 + w0);
    #pragma unroll
    for (int nf = 0; nf < NF; ++nf) {
      const int ch = wave_n * (COUT / 2) + nf * 16 + j15;
      #pragma unroll
      for (int mf = 0; mf < 2; ++mf)
        #pragma unroll
        for (int r4 = 0; r4 < 4; ++r4) {
          float y = acc[rr][mf][nf][r4] + bv[nf];
          sa[nf] += y; qa[nf] += y * y;
          if constexpr (WRITE_OUT) {
            const int p = wave_m * 32 + mf * 16 + q4 * 4 + r4;
            out[(orow + p) * COUT + ch] = f2bf(y);
          }
        }
    }
  }

  __syncthreads();
  float* red = (float*)lds;
  #pragma unroll
  for (int nf = 0; nf < NF; ++nf) {
    float s = sa[nf], q = qa[nf];
    s += __shfl_xor(s, 16); s += __shfl_xor(s, 32);
    q += __shfl_xor(q, 16); q += __shfl_xor(q, 32);
    if (lane < 16) {
      red[(wv * NF + nf) * 16 + lane] = s;
      red[4 * NF * 16 + (wv * NF + nf) * 16 + lane] = q;
    }
  }
  __syncthreads();
  if (tid < COUT) {
    const int wn = tid / (COUT / 2), rr = tid % (COUT / 2);
    const int nf = rr >> 4, li = rr & 15;
    float s = red[(wn * NF + nf) * 16 + li] + red[((wn + 2) * NF + nf) * 16 + li];
    float q = red[4 * NF * 16 + (wn * NF + nf) * 16 + li] +
              red[4 * NF * 16 + ((wn + 2) * NF + nf) * 16 + li];
    const int sl = lin & (NSLOT - 1);
    atomicAdd(&totals_out[((size_t)sl * 2 + 0) * COUT + tid], s);
    atomicAdd(&totals_out[((size_t)sl * 2 + 1) * COUT + tid], q);
  }
}

// ---- fused outputs: patches (blocks 0..13) + encode (blocks 14..21) -------
__global__ __launch_bounds__(256) void outputs_kernel(
    const float* __restrict__ img, const int* __restrict__ axy,
    const int* __restrict__ pxy, const int* __restrict__ nxy,
    const unsigned short* __restrict__ y2, const float* __restrict__ wgt,
    const float* __restrict__ bias,
    const float* __restrict__ totals2, const float* __restrict__ g2,
    const float* __restrict__ b2v,
    const float* __restrict__ totals3, const float* __restrict__ g3,
    const float* __restrict__ b3v,
    float* __restrict__ out)
{
  if (blockIdx.x < 14) {
    const int i = blockIdx.x * 256 + threadIdx.x;
    if (i >= 3 * BATCH * 3 * 49) return;
    const int arr = i / 1176, r = i % 1176;
    const int b = r / 147, q = r % 147;
    const int c = q / 49, s = q % 49;
    const int ph = s / 7, pw = s % 7;
    const int* xy = (arr == 0) ? axy : ((arr == 1) ? pxy : nxy);
    const int x = xy[(b * 32 + 31) * 2 + 0];
    const int y = xy[(b * 32 + 31) * 2 + 1];
    out[i] = img[((size_t)(b * 3 + c) * HH + (x - 3 + ph)) * WW + (y - 3 + pw)];
  } else {
    const int b = blockIdx.x - 14;         // 0..7
    const int x = nxy[(b * 32 + 31) * 2 + 0];
    const int y = nxy[(b * 32 + 31) * 2 + 1];
    __shared__ float sc2[2][64], sc3[2][128];
    __shared__ float act[576];             // k = ci*9 + dh*3 + dw
    if (threadIdx.x < 64) {
      float s = 0.f, q = 0.f;
      for (int i = 0; i < NSLOT; ++i) {
        s += totals2[((size_t)i * 2 + 0) * 64 + threadIdx.x];
        q += totals2[((size_t)i * 2 + 1) * 64 + threadIdx.x];
      }
      const float mean = s / BN_N;
      const float var = q / BN_N - mean * mean;
      const float rstd = rsqrtf(var + 1e-5f);
      const float sc = g2[threadIdx.x] * rstd;
      sc2[0][threadIdx.x] = sc;
      sc2[1][threadIdx.x] = b2v[threadIdx.x] - mean * sc;
    } else if (threadIdx.x >= 128) {
      const int c = threadIdx.x - 128;
      float s = 0.f, q = 0.f;
      for (int i = 0; i < NSLOT; ++i) {
        s += totals3[((size_t)i * 2 + 0) * 128 + c];
        q += totals3[((size_t)i * 2 + 1) * 128 + c];
      }
      const float mean = s / BN_N;
      const float var = q / BN_N - mean * mean;
      const float rstd = rsqrtf(var + 1e-5f);
      const float sc = g3[c] * rstd;
      sc3[0][c] = sc;
      sc3[1][c] = b3v[c] - mean * sc;
    }
    __syncthreads();
    for (int t = threadIdx.x; t < 576; t += 256) {
      const int ci = t / 9, tap = t - ci * 9;
      const int dh = tap / 3, dw = tap - dh * 3;
      float v = bf2f(y2[((size_t)(b * 256 + (x + dh - 1)) * 256 + (y + dw - 1)) * 64 + ci]);
      v = v * sc2[0][ci] + sc2[1][ci];
      act[t] = fmaxf(v, 0.01f * v);
    }
    __syncthreads();
    if (threadIdx.x < 128) {
      const int co = threadIdx.x;
      float acc = bias[co];
      const float4* w4 = (const float4*)(wgt + (size_t)co * 576);
      #pragma unroll 9
      for (int kk = 0; kk < 144; ++kk) {
        const float4 wv = w4[kk];
        acc = fmaf(wv.x, act[4 * kk + 0], acc);
        acc = fmaf(wv.y, act[4 * kk + 1], acc);
        acc = fmaf(wv.z, act[4 * kk + 2], acc);
        acc = fmaf(wv.w, act[4 * kk + 3], acc);
      }
      const float yv = acc * sc3[0][co] + sc3[1][co];
      out[3528 + b * 128 + co] = fmaxf(yv, 0.01f * yv);
    }
  }
}

extern "C" void kernel_launch(void* const* d_in, const int* in_sizes, int n_in,
                              void* d_out, int out_size, void* d_ws, size_t ws_size,
                              hipStream_t stream)
{
  const float* image = (const float*)d_in[0];
  const int* axy = (const int*)d_in[1];
  const int* pxy = (const int*)d_in[2];
  const int* nxy = (const int*)d_in[3];
  const float* c1w = (const float*)d_in[4];
  const float* c1b = (const float*)d_in[5];
  const float* g1 = (const float*)d_in[6];
  const float* b1 = (const float*)d_in[7];
  const float* c2w = (const float*)d_in[8];
  const float* c2b = (const float*)d_in[9];
  const float* g2 = (const float*)d_in[10];
  const float* b2 = (const float*)d_in[11];
  const float* c3w = (const float*)d_in[12];
  const float* c3b = (const float*)d_in[13];
  const float* g3 = (const float*)d_in[14];
  const float* b3 = (const float*)d_in[15];
  float* out = (float*)d_out;

  // workspace layout (~101 MB)
  unsigned short* zb1 = (unsigned short*)d_ws;            // raw y1, 16.78M bf16
  unsigned short* zb2 = zb1 + (size_t)8 * 32 * HWSZ;      // raw y2, 33.55M bf16
  unsigned short* wf2 = zb2 + (size_t)8 * 64 * HWSZ;      // 18432
  unsigned short* wf3 = wf2 + 18432;                      // 73728
  float* totals1 = (float*)(wf3 + 73728);                 // 64*2*32  = 4096
  float* totals2 = totals1 + (size_t)NSLOT * 2 * 32;      // 64*2*64  = 8192
  float* totals3 = totals2 + (size_t)NSLOT * 2 * 64;      // 64*2*128 = 16384

  // zero the 64-slot stat accumulators (28672 floats)
  hipMemsetAsync(totals1, 0, (size_t)NSLOT * 2 * (32 + 64 + 128) * sizeof(float),
                 stream);

  // conv1 via MFMA R=4 (blocks 0..2047) + wf2/wf3 prep (blocks 2048..2407)
  conv1_mfma<<<2408, 256, 0, stream>>>(
      image, c1w, c1b, zb1, totals1, c2w, c3w, wf2, wf3);

  // layer 2: 32 -> 64 (MFMA, R=4; bn1 folded inline)
  conv_mfma<32, 64, 4, true, 2><<<2048, 256, 0, stream>>>(
      zb1, wf2, c2b, totals1, g1, b1, zb2, totals2);

  // layer 3: 64 -> 128 (MFMA, R=2, MINW=4 register-pack probe; bn2 inline)
  conv_mfma<64, 128, 2, false, 4><<<4096, 256, 0, stream>>>(
      zb2, wf3, c3b, totals2, g2, b2, nullptr, totals3);

  // outputs: patches (0..13) + per-batch encode (14..21), bn folds inline
  outputs_kernel<<<22, 256, 0, stream>>>(image, axy, pxy, nxy, zb2, c3w, c3b,
                                         totals2, g2, b2, totals3, g3, b3, out);
}

// Round 19
// 233.586 us; speedup vs baseline: 1.1813x; 1.1813x over previous
//
#include <hip/hip_runtime.h>
#include <math.h>

#define HH 256
#define WW 256
#define BATCH 8
#define HWSZ 65536
#define BN_N 524288.0f  // BATCH*HWSZ
#define NSLOT 64        // stat-slot spreading factor

typedef __attribute__((ext_vector_type(8))) short short8;
typedef __attribute__((ext_vector_type(4))) float floatx4;

// round-half-up bf16 pack: 2 VALU ops, max err 0.5 ulp
__device__ __forceinline__ unsigned short f2bf(float f) {
  union { float f; unsigned int u; } v; v.f = f;
  return (unsigned short)((v.u + 0x8000u) >> 16);
}
// pack two fp32 -> bf16x2 (lo=a, hi=d): 5 VALU ops
__device__ __forceinline__ unsigned int pack2bf(float a, float d) {
  union { float f; unsigned int u; } va, vd; va.f = a; vd.f = d;
  return ((va.u + 0x8000u) >> 16) | ((vd.u + 0x8000u) & 0xffff0000u);
}
__device__ __forceinline__ float bf2f(unsigned short u) {
  union { unsigned int u; float f; } v; v.u = ((unsigned int)u) << 16;
  return v.f;
}

// ---- conv1 as im2col MFMA, R=4 (blocks 0..2047) + wf prep (2048..2407) ----
// Stage 6 rows x 66 px (1.5x redundancy); 8 MFMA/wave.
__global__ __launch_bounds__(256) void conv1_mfma(
    const float* __restrict__ img, const float* __restrict__ w1,
    const float* __restrict__ bias, unsigned short* __restrict__ out,
    float* __restrict__ totals1,
    const float* __restrict__ w2, const float* __restrict__ w3,
    unsigned short* __restrict__ wf2, unsigned short* __restrict__ wf3)
{
  const int lin = blockIdx.x;
  if (lin >= 2048) {  // ---- prep path: 360 blocks cover 92160 elems ----
    int idx = (lin - 2048) * 256 + threadIdx.x;
    if (idx < 18432) {  // conv2: CIN=32, COUT=64, KC=1, NG=4
      const int j = idx & 7;
      const int lane = (idx >> 3) & 63;
      int rest = idx >> 9;
      const int ng = rest % 4;
      const int tap = rest / 4;
      const int cout = ng * 16 + (lane & 15);
      const int cin = ((lane >> 4) << 3) + j;
      wf2[idx] = f2bf(w2[((size_t)cout * 32 + cin) * 9 + tap]);
    } else {            // conv3: CIN=64, COUT=128, KC=2, NG=8
      idx -= 18432;
      if (idx >= 73728) return;
      const int j = idx & 7;
      const int lane = (idx >> 3) & 63;
      int rest = idx >> 9;
      const int ng = rest % 8; rest /= 8;
      const int kc = rest & 1;
      const int tap = rest >> 1;
      const int cout = ng * 16 + (lane & 15);
      const int cin = kc * 32 + ((lane >> 4) << 3) + j;
      wf3[idx] = f2bf(w3[((size_t)cout * 64 + cin) * 9 + tap]);
    }
    return;
  }

  const int tid = threadIdx.x, lane = tid & 63, wv = tid >> 6;
  const int wave_m = wv >> 1, wave_n = wv & 1;
  const int xcd = lin & 7, slot = lin >> 3;
  const int b = slot >> 5;            // 32 slots per batch
  const int rem = slot & 31;
  const int h0 = ((xcd << 3) + (rem >> 2)) * 4;
  const int w0 = (rem & 3) * 64;

  __shared__ __align__(16) unsigned short simg[6 * 66 * 4];  // [row][px][3ch+pad]
  __shared__ __align__(16) unsigned short swf[2 * 64 * 8];   // conv1 B-frags
  __shared__ float red2[2][4][16];                           // [s|q][wv][li]

  for (int t = tid; t < (6 * 66 * 4) / 2; t += 256)
    ((unsigned int*)simg)[t] = 0u;
  {
    const int t0 = tid * 4;
    #pragma unroll
    for (int u = 0; u < 4; ++u) {
      const int idx = t0 + u;
      const int j = idx & 7, l8 = (idx >> 3) & 63, nt = idx >> 9;
      const int k = ((l8 >> 4) << 3) + j;
      const int cout = nt * 16 + (l8 & 15);
      swf[idx] = (k < 27) ? f2bf(w1[cout * 27 + k]) : (unsigned short)0;
    }
  }
  __syncthreads();
  for (int t = tid; t < 3 * 6 * 66; t += 256) {
    const int ci = t / 396, r2 = t - ci * 396;
    const int r = r2 / 66, px = r2 - r * 66;
    const int hi = h0 + r - 1, wi = w0 + px - 1;
    if ((unsigned)hi < 256u && (unsigned)wi < 256u)
      simg[(r * 66 + px) * 4 + ci] =
          f2bf(img[((size_t)(b * 3 + ci) * 256 + hi) * 256 + wi]);
  }
  __syncthreads();

  const int j15 = lane & 15, q4 = lane >> 4;
  int off[8];
  #pragma unroll
  for (int j = 0; j < 8; ++j) {
    const int k = q4 * 8 + j;
    const int ci = k / 9, tap = k - ci * 9;
    const int dh = tap / 3, dw = tap - dh * 3;
    off[j] = (dh * 66 + dw) * 4 + ci;
  }
  const int base_px = wave_m * 32 + j15;
  const short8 bg = *(const short8*)&swf[(wave_n * 64 + lane) * 8];

  floatx4 acc[4][2];
  #pragma unroll
  for (int rr = 0; rr < 4; ++rr)
    #pragma unroll
    for (int mf = 0; mf < 2; ++mf) {
      acc[rr][mf] = (floatx4){0.f, 0.f, 0.f, 0.f};
      union { short8 v; unsigned short e[8]; } a;
      const int ab = (rr * 66 + base_px + mf * 16) * 4;
      #pragma unroll
      for (int j = 0; j < 8; ++j) a.e[j] = simg[ab + off[j]];
      acc[rr][mf] = __builtin_amdgcn_mfma_f32_16x16x32_bf16(a.v, bg, acc[rr][mf], 0, 0, 0);
    }

  float sa = 0.f, qa = 0.f;
  const float bv = bias[wave_n * 16 + j15];
  #pragma unroll
  for (int rr = 0; rr < 4; ++rr) {
    const size_t orow = ((size_t)(b * 256 + (h0 + rr)) * 256 + w0);
    #pragma unroll
    for (int mf = 0; mf < 2; ++mf)
      #pragma unroll
      for (int r4 = 0; r4 < 4; ++r4) {
        float y = acc[rr][mf][r4] + bv;
        sa += y; qa += y * y;
        const int p = wave_m * 32 + mf * 16 + q4 * 4 + r4;
        out[(orow + p) * 32 + wave_n * 16 + j15] = f2bf(y);
      }
  }
  sa += __shfl_xor(sa, 16); sa += __shfl_xor(sa, 32);
  qa += __shfl_xor(qa, 16); qa += __shfl_xor(qa, 32);
  if (lane < 16) { red2[0][wv][lane] = sa; red2[1][wv][lane] = qa; }
  __syncthreads();
  if (tid < 64) {
    const int c = tid >> 1, jj = tid & 1;
    const int wn = c >> 4, li = c & 15;
    const float r = red2[jj][wn][li] + red2[jj][wn + 2][li];
    atomicAdd(&totals1[(((size_t)(lin & (NSLOT - 1)) * 2 + jj)) * 32 + c], r);
  }
}

// ---- MFMA conv: 64px x R ROWS x COUT per block, PADDED affine LDS ---------
// MINW=2 for both (MINW=4 forces VGPR<=64 -> acc spill, measured 224MB
// scratch writes + 1.6x slowdown in R18 -- do not raise).
template<int CIN, int COUT, int R, bool WRITE_OUT, int MINW>
__global__ __launch_bounds__(256, MINW) void conv_mfma(
    const unsigned short* __restrict__ in, const unsigned short* __restrict__ wf,
    const float* __restrict__ bias,
    const float* __restrict__ totals_in, const float* __restrict__ gamma_in,
    const float* __restrict__ beta_in,
    unsigned short* __restrict__ out, float* __restrict__ totals_out)
{
  constexpr int KC = CIN / 32;
  constexpr int NG = COUT / 16;
  constexpr int NF = COUT / 32;
  constexpr int CH8 = CIN / 8;
  constexpr int CH8_LOG = (CH8 == 4) ? 2 : 3;
  constexpr int CPAD = CIN + 8;
  constexpr int GRP = 256 / CIN;        // fold groups
  constexpr int SPG = NSLOT / GRP;      // slots per group
  constexpr int ROWS = R + 2;           // staged rows
  constexpr int HT8 = (256 / R) / 8;    // h-tiles per XCD per batch
  constexpr int SLB = (256 / R) / 2;    // slots per batch

  const int tid = threadIdx.x, lane = tid & 63, wv = tid >> 6;
  const int wave_m = wv >> 1, wave_n = wv & 1;

  const int lin = blockIdx.x;
  const int xcd = lin & 7, slot = lin >> 3;
  const int b = slot / SLB;
  const int rem = slot % SLB;
  const int h0 = (xcd * HT8 + (rem >> 2)) * R;
  const int w0 = (rem & 3) * 64;
  const size_t inb = (size_t)b * HWSZ * CIN;

  __shared__ __align__(16) unsigned short lds[ROWS * 66 * CPAD];
  __shared__ __align__(16) float scsh[2][CIN];

  // parallel BN fold: 256 threads cover NSLOT slots in GRP groups
  {
    const int c = tid % CIN, g = tid / CIN;
    float ps = 0.f, pq = 0.f;
    #pragma unroll
    for (int i = 0; i < SPG; ++i) {
      const int sl = g * SPG + i;
      ps += totals_in[((size_t)sl * 2 + 0) * CIN + c];
      pq += totals_in[((size_t)sl * 2 + 1) * CIN + c];
    }
    float* pf = (float*)lds;  // [2][GRP][CIN] partials (staging overwrites later)
    pf[(0 * GRP + g) * CIN + c] = ps;
    pf[(1 * GRP + g) * CIN + c] = pq;
    __syncthreads();
    if (tid < CIN) {
      float s = 0.f, q = 0.f;
      #pragma unroll
      for (int g2 = 0; g2 < GRP; ++g2) {
        s += pf[(0 * GRP + g2) * CIN + tid];
        q += pf[(1 * GRP + g2) * CIN + tid];
      }
      const float mean = s / BN_N;
      const float var = q / BN_N - mean * mean;
      const float rstd = rsqrtf(var + 1e-5f);
      const float sc = gamma_in[tid] * rstd;
      scsh[0][tid] = sc;
      scsh[1][tid] = beta_in[tid] - mean * sc;
    }
    __syncthreads();
  }

  // staging: fixed ck per thread; scale/shift regs loaded ONCE
  {
    const int ck = tid & (CH8 - 1);
    const float4 s0 = *(const float4*)&scsh[0][ck * 8];
    const float4 s1 = *(const float4*)&scsh[0][ck * 8 + 4];
    const float4 t0 = *(const float4*)&scsh[1][ck * 8];
    const float4 t1 = *(const float4*)&scsh[1][ck * 8 + 4];
    const float scs[8] = {s0.x, s0.y, s0.z, s0.w, s1.x, s1.y, s1.z, s1.w};
    const float shs[8] = {t0.x, t0.y, t0.z, t0.w, t1.x, t1.y, t1.z, t1.w};
    for (int rpx = tid >> CH8_LOG; rpx < ROWS * 66; rpx += 256 >> CH8_LOG) {
      const int r = rpx / 66, px = rpx - r * 66;
      const int hi = h0 + r - 1, wi = w0 - 1 + px;
      uint4 v = make_uint4(0u, 0u, 0u, 0u);
      if ((unsigned)hi < 256u && (unsigned)wi < 256u) {
        uint4 raw = *(const uint4*)&in[inb + ((size_t)hi * 256 + wi) * CIN + ck * 8];
        unsigned int* u = (unsigned int*)&raw;
        unsigned int* o = (unsigned int*)&v;
        #pragma unroll
        for (int p = 0; p < 4; ++p) {
          float a = bf2f((unsigned short)(u[p] & 0xffff));
          float d = bf2f((unsigned short)(u[p] >> 16));
          float ya = a * scs[2 * p] + shs[2 * p];
          float yd = d * scs[2 * p + 1] + shs[2 * p + 1];
          ya = fmaxf(ya, 0.01f * ya);
          yd = fmaxf(yd, 0.01f * yd);
          o[p] = pack2bf(ya, yd);
        }
      }
      *(uint4*)&lds[rpx * CPAD + ck * 8] = v;
    }
  }
  __syncthreads();

  const int j15 = lane & 15, q4 = lane >> 4;
  const int base_px = wave_m * 32 + j15;
  const unsigned short* abase = &lds[base_px * CPAD + q4 * 8];

  floatx4 acc[R][2][NF];
  #pragma unroll
  for (int rr = 0; rr < R; ++rr)
    #pragma unroll
    for (int mf = 0; mf < 2; ++mf)
      #pragma unroll
      for (int nf = 0; nf < NF; ++nf) acc[rr][mf][nf] = (floatx4){0.f, 0.f, 0.f, 0.f};

  #pragma unroll
  for (int dh = 0; dh < 3; ++dh) {
    #pragma unroll
    for (int dw = 0; dw < 3; ++dw) {
      #pragma unroll
      for (int kc = 0; kc < KC; ++kc) {
        const int tap = dh * 3 + dw;
        short8 bg[NF];
        #pragma unroll
        for (int nf = 0; nf < NF; ++nf)
          bg[nf] = *(const short8*)&wf[((((tap * KC + kc) * NG) + wave_n * NF + nf) * 64 + lane) * 8];
        #pragma unroll
        for (int rr = 0; rr < R; ++rr) {
          short8 a[2];
          #pragma unroll
          for (int mf = 0; mf < 2; ++mf)
            a[mf] = *(const short8*)&abase[((rr + dh) * 66 + dw + mf * 16) * CPAD + kc * 32];
          #pragma unroll
          for (int mf = 0; mf < 2; ++mf)
            #pragma unroll
            for (int nf = 0; nf < NF; ++nf)
              acc[rr][mf][nf] = __builtin_amdgcn_mfma_f32_16x16x32_bf16(a[mf], bg[nf], acc[rr][mf][nf], 0, 0, 0);
        }
      }
    }
  }

  float bv[NF], sa[NF], qa[NF];
  #pragma unroll
  for (int nf = 0; nf < NF; ++nf) {
    bv[nf] = bias[wave_n * (COUT / 2) + nf * 16 + j15];
    sa[nf] = 0.f; qa[nf] = 0.f;
  }
  #pragma unroll
  for (int rr = 0; rr < R; ++rr) {
    const size_t orow = ((size_t)(b * 256 + (h0 + rr)) * 256 + w0);
    #pragma unroll
    for (int nf = 0; nf < NF; ++nf) {
      const int ch = wave_n * (COUT / 2) + nf * 16 + j15;
      #pragma unroll
      for (int mf = 0; mf < 2; ++mf)
        #pragma unroll
        for (int r4 = 0; r4 < 4; ++r4) {
          float y = acc[rr][mf][nf][r4] + bv[nf];
          sa[nf] += y; qa[nf] += y * y;
          if constexpr (WRITE_OUT) {
            const int p = wave_m * 32 + mf * 16 + q4 * 4 + r4;
            out[(orow + p) * COUT + ch] = f2bf(y);
          }
        }
    }
  }

  __syncthreads();
  float* red = (float*)lds;
  #pragma unroll
  for (int nf = 0; nf < NF; ++nf) {
    float s = sa[nf], q = qa[nf];
    s += __shfl_xor(s, 16); s += __shfl_xor(s, 32);
    q += __shfl_xor(q, 16); q += __shfl_xor(q, 32);
    if (lane < 16) {
      red[(wv * NF + nf) * 16 + lane] = s;
      red[4 * NF * 16 + (wv * NF + nf) * 16 + lane] = q;
    }
  }
  __syncthreads();
  if (tid < COUT) {
    const int wn = tid / (COUT / 2), rr = tid % (COUT / 2);
    const int nf = rr >> 4, li = rr & 15;
    float s = red[(wn * NF + nf) * 16 + li] + red[((wn + 2) * NF + nf) * 16 + li];
    float q = red[4 * NF * 16 + (wn * NF + nf) * 16 + li] +
              red[4 * NF * 16 + ((wn + 2) * NF + nf) * 16 + li];
    const int sl = lin & (NSLOT - 1);
    atomicAdd(&totals_out[((size_t)sl * 2 + 0) * COUT + tid], s);
    atomicAdd(&totals_out[((size_t)sl * 2 + 1) * COUT + tid], q);
  }
}

// ---- fused outputs: patches (blocks 0..13) + encode (blocks 14..21) -------
__global__ __launch_bounds__(256) void outputs_kernel(
    const float* __restrict__ img, const int* __restrict__ axy,
    const int* __restrict__ pxy, const int* __restrict__ nxy,
    const unsigned short* __restrict__ y2, const float* __restrict__ wgt,
    const float* __restrict__ bias,
    const float* __restrict__ totals2, const float* __restrict__ g2,
    const float* __restrict__ b2v,
    const float* __restrict__ totals3, const float* __restrict__ g3,
    const float* __restrict__ b3v,
    float* __restrict__ out)
{
  if (blockIdx.x < 14) {
    const int i = blockIdx.x * 256 + threadIdx.x;
    if (i >= 3 * BATCH * 3 * 49) return;
    const int arr = i / 1176, r = i % 1176;
    const int b = r / 147, q = r % 147;
    const int c = q / 49, s = q % 49;
    const int ph = s / 7, pw = s % 7;
    const int* xy = (arr == 0) ? axy : ((arr == 1) ? pxy : nxy);
    const int x = xy[(b * 32 + 31) * 2 + 0];
    const int y = xy[(b * 32 + 31) * 2 + 1];
    out[i] = img[((size_t)(b * 3 + c) * HH + (x - 3 + ph)) * WW + (y - 3 + pw)];
  } else {
    const int b = blockIdx.x - 14;         // 0..7
    const int x = nxy[(b * 32 + 31) * 2 + 0];
    const int y = nxy[(b * 32 + 31) * 2 + 1];
    __shared__ float sc2[2][64], sc3[2][128];
    __shared__ float act[576];             // k = ci*9 + dh*3 + dw
    if (threadIdx.x < 64) {
      float s = 0.f, q = 0.f;
      for (int i = 0; i < NSLOT; ++i) {
        s += totals2[((size_t)i * 2 + 0) * 64 + threadIdx.x];
        q += totals2[((size_t)i * 2 + 1) * 64 + threadIdx.x];
      }
      const float mean = s / BN_N;
      const float var = q / BN_N - mean * mean;
      const float rstd = rsqrtf(var + 1e-5f);
      const float sc = g2[threadIdx.x] * rstd;
      sc2[0][threadIdx.x] = sc;
      sc2[1][threadIdx.x] = b2v[threadIdx.x] - mean * sc;
    } else if (threadIdx.x >= 128) {
      const int c = threadIdx.x - 128;
      float s = 0.f, q = 0.f;
      for (int i = 0; i < NSLOT; ++i) {
        s += totals3[((size_t)i * 2 + 0) * 128 + c];
        q += totals3[((size_t)i * 2 + 1) * 128 + c];
      }
      const float mean = s / BN_N;
      const float var = q / BN_N - mean * mean;
      const float rstd = rsqrtf(var + 1e-5f);
      const float sc = g3[c] * rstd;
      sc3[0][c] = sc;
      sc3[1][c] = b3v[c] - mean * sc;
    }
    __syncthreads();
    for (int t = threadIdx.x; t < 576; t += 256) {
      const int ci = t / 9, tap = t - ci * 9;
      const int dh = tap / 3, dw = tap - dh * 3;
      float v = bf2f(y2[((size_t)(b * 256 + (x + dh - 1)) * 256 + (y + dw - 1)) * 64 + ci]);
      v = v * sc2[0][ci] + sc2[1][ci];
      act[t] = fmaxf(v, 0.01f * v);
    }
    __syncthreads();
    if (threadIdx.x < 128) {
      const int co = threadIdx.x;
      float acc = bias[co];
      const float4* w4 = (const float4*)(wgt + (size_t)co * 576);
      #pragma unroll 9
      for (int kk = 0; kk < 144; ++kk) {
        const float4 wv = w4[kk];
        acc = fmaf(wv.x, act[4 * kk + 0], acc);
        acc = fmaf(wv.y, act[4 * kk + 1], acc);
        acc = fmaf(wv.z, act[4 * kk + 2], acc);
        acc = fmaf(wv.w, act[4 * kk + 3], acc);
      }
      const float yv = acc * sc3[0][co] + sc3[1][co];
      out[3528 + b * 128 + co] = fmaxf(yv, 0.01f * yv);
    }
  }
}

extern "C" void kernel_launch(void* const* d_in, const int* in_sizes, int n_in,
                              void* d_out, int out_size, void* d_ws, size_t ws_size,
                              hipStream_t stream)
{
  const float* image = (const float*)d_in[0];
  const int* axy = (const int*)d_in[1];
  const int* pxy = (const int*)d_in[2];
  const int* nxy = (const int*)d_in[3];
  const float* c1w = (const float*)d_in[4];
  const float* c1b = (const float*)d_in[5];
  const float* g1 = (const float*)d_in[6];
  const float* b1 = (const float*)d_in[7];
  const float* c2w = (const float*)d_in[8];
  const float* c2b = (const float*)d_in[9];
  const float* g2 = (const float*)d_in[10];
  const float* b2 = (const float*)d_in[11];
  const float* c3w = (const float*)d_in[12];
  const float* c3b = (const float*)d_in[13];
  const float* g3 = (const float*)d_in[14];
  const float* b3 = (const float*)d_in[15];
  float* out = (float*)d_out;

  // workspace layout (~101 MB)
  unsigned short* zb1 = (unsigned short*)d_ws;            // raw y1, 16.78M bf16
  unsigned short* zb2 = zb1 + (size_t)8 * 32 * HWSZ;      // raw y2, 33.55M bf16
  unsigned short* wf2 = zb2 + (size_t)8 * 64 * HWSZ;      // 18432
  unsigned short* wf3 = wf2 + 18432;                      // 73728
  float* totals1 = (float*)(wf3 + 73728);                 // 64*2*32  = 4096
  float* totals2 = totals1 + (size_t)NSLOT * 2 * 32;      // 64*2*64  = 8192
  float* totals3 = totals2 + (size_t)NSLOT * 2 * 64;      // 64*2*128 = 16384

  // zero the 64-slot stat accumulators (28672 floats)
  hipMemsetAsync(totals1, 0, (size_t)NSLOT * 2 * (32 + 64 + 128) * sizeof(float),
                 stream);

  // conv1 via MFMA R=4 (blocks 0..2047) + wf2/wf3 prep (blocks 2048..2407)
  conv1_mfma<<<2408, 256, 0, stream>>>(
      image, c1w, c1b, zb1, totals1, c2w, c3w, wf2, wf3);

  // layer 2: 32 -> 64 (MFMA, R=4; bn1 folded inline)
  conv_mfma<32, 64, 4, true, 2><<<2048, 256, 0, stream>>>(
      zb1, wf2, c2b, totals1, g1, b1, zb2, totals2);

  // layer 3: 64 -> 128 (MFMA, R=2, MINW=2 -- proven config; bn2 inline)
  conv_mfma<64, 128, 2, false, 2><<<4096, 256, 0, stream>>>(
      zb2, wf3, c3b, totals2, g2, b2, nullptr, totals3);

  // outputs: patches (0..13) + per-batch encode (14..21), bn folds inline
  outputs_kernel<<<22, 256, 0, stream>>>(image, axy, pxy, nxy, zb2, c3w, c3b,
                                         totals2, g2, b2, totals3, g3, b3, out);
}